// Round 4
// baseline (499.040 us; speedup 1.0000x reference)
//
#include <hip/hip_runtime.h>

#define V 4096
#define H 256
#define O 512
#define B 64
#define T 512

typedef __attribute__((ext_vector_type(8))) short bf16x8;
typedef __attribute__((ext_vector_type(4))) float f32x4;
typedef __attribute__((ext_vector_type(2))) float f32x2;

__device__ __forceinline__ unsigned short f2bf(float f) {
    unsigned int u = __float_as_uint(f);
    u += 0x7fffu + ((u >> 16) & 1u);   // round-to-nearest-even
    return (unsigned short)(u >> 16);
}
__device__ __forceinline__ float bf2f(unsigned short s) {
    return __uint_as_float(((unsigned int)s) << 16);
}

// DPP quad-perm add helpers (pure VALU cross-lane, zero DS-pipe cost)
__device__ __forceinline__ float dpp_xor1(float v) {
    int i = __float_as_int(v);
    int r = __builtin_amdgcn_update_dpp(i, i, 0xB1, 0xf, 0xf, true); // quad_perm[1,0,3,2]
    return __int_as_float(r);
}
__device__ __forceinline__ float dpp_xor2(float v) {
    int i = __float_as_int(v);
    int r = __builtin_amdgcn_update_dpp(i, i, 0x4E, 0xf, 0xf, true); // quad_perm[2,3,0,1]
    return __int_as_float(r);
}

// ---------------------------------------------------------------------------
// K1a: transpose W_ih [H][V] -> WihT [V][H] (coalesced per-step gather rows).
// ---------------------------------------------------------------------------
__global__ __launch_bounds__(256) void k_transpose(const float* __restrict__ Wih,
                                                   float* __restrict__ WihT) {
    __shared__ float tile[64][65];
    const int bi = blockIdx.x & 3;
    const int bv = blockIdx.x >> 2;
    const int tx = threadIdx.x & 63, ty = threadIdx.x >> 6;
#pragma unroll
    for (int s = 0; s < 16; ++s) {
        int r = ty + 4 * s;
        tile[r][tx] = Wih[(size_t)(bi * 64 + r) * V + bv * 64 + tx];
    }
    __syncthreads();
#pragma unroll
    for (int s = 0; s < 16; ++s) {
        int r = ty + 4 * s;
        WihT[(size_t)(bv * 64 + r) * H + bi * 64 + tx] = tile[tx][r];
    }
}

// ---------------------------------------------------------------------------
// K1b: split W_fc into bf16 hi + bf16 lo for the 3-MFMA FC.
// ---------------------------------------------------------------------------
__global__ __launch_bounds__(256) void k_prep(const float* __restrict__ Wfc,
                                              unsigned short* __restrict__ hi,
                                              unsigned short* __restrict__ lo) {
    int i = blockIdx.x * 256 + threadIdx.x;
    float w = Wfc[i];
    unsigned short h = f2bf(w);
    hi[i] = h;
    lo[i] = f2bf(w - bf2f(h));
}

// ---------------------------------------------------------------------------
// K2: persistent RNN. 64 blocks x 256 threads (1 wave/SIMD, 512-VGPR budget).
// Thread (g = tid>>3, c = tid&7): rows 8g..8g+7, k-eighth c (32 terms).
// Weights: 64 x f32x4 = 256 VGPRs, asm-pinned. h in LDS, 36-float padded
// chunks: for each j, the 8 c-addresses cover all 32 banks (conflict-free
// broadcast). Reduce: xor1/xor2 DPP adds (VALU) + ONE ds_swizzle (xor4)
// after a 7-cndmask narrowing select. One tanh per thread (row 8g+c).
// ---------------------------------------------------------------------------
#define CH8 36   // padded chunk stride in floats (32 data + 4 pad)

__global__ __launch_bounds__(256, 1) void k_rnn(
    const int* __restrict__ x, const float* __restrict__ WihT,
    const float* __restrict__ Whh, const float* __restrict__ b_ih,
    const float* __restrict__ b_hh,
    unsigned short* __restrict__ hs_hi, unsigned short* __restrict__ hs_lo) {
    __shared__ float hsm[2][8 * CH8];
    __shared__ int xs[T];
    const int b = blockIdx.x;
    const int tid = threadIdx.x;
    const int g = tid >> 3;      // row-group 0..31 (8 rows each)
    const int c = tid & 7;       // k-eighth 0..7 (32 terms)
    const int row = 8 * g + c;   // the row this lane finalizes
    const int k0 = 32 * c;

    // W_hh rows 8g..8g+7, k in [k0, k0+32): 64 f32x4 = 256 VGPRs
    f32x4 w4[8][8];
#pragma unroll
    for (int r = 0; r < 8; ++r) {
        const f32x4* wr = (const f32x4*)(Whh + (size_t)(8 * g + r) * H + k0);
#pragma unroll
        for (int j = 0; j < 8; ++j) w4[r][j] = wr[j];
    }
#pragma unroll
    for (int r = 0; r < 8; ++r)
#pragma unroll
        for (int j = 0; j < 8; ++j)
            asm volatile("" : "+v"(w4[r][j]));   // opaque: no remat/reload

    xs[tid] = x[b * T + tid];
    xs[tid + 256] = x[b * T + tid + 256];
    for (int s = tid; s < 8 * CH8; s += 256) hsm[0][s] = 0.0f;
    const float bias = b_ih[row] + b_hh[row];
    __syncthreads();

    unsigned short* ph = hs_hi + (size_t)b * T * H + row;
    unsigned short* pl = hs_lo + (size_t)b * T * H + row;

    float xp_cur = WihT[(size_t)xs[0] * H + row];
    unsigned short hh_prev = 0, hl_prev = 0;

    for (int t = 0; t < T; ++t) {
        // store h_{t-1} (fire-and-forget; drains under this step's dot)
        if (t > 0) {
            ph[(size_t)(t - 1) * H] = hh_prev;
            pl[(size_t)(t - 1) * H] = hl_prev;
        }
        // prefetch next step's gather element
        int tn = (t + 1 < T) ? t + 1 : t;
        float xp_next = WihT[(size_t)xs[tn] * H + row];

        const f32x4* hv = (const f32x4*)(hsm[t & 1] + c * CH8);
        f32x4 a0 = {0,0,0,0}, a1 = {0,0,0,0}, a2 = {0,0,0,0}, a3 = {0,0,0,0};
        f32x4 a4 = {0,0,0,0}, a5 = {0,0,0,0}, a6 = {0,0,0,0}, a7 = {0,0,0,0};
#pragma unroll
        for (int j = 0; j < 8; ++j) {
            f32x4 h4 = hv[j];    // 8 distinct addrs (one per c) cover 32 banks
            a0 += h4 * w4[0][j];
            a1 += h4 * w4[1][j];
            a2 += h4 * w4[2][j];
            a3 += h4 * w4[3][j];
            a4 += h4 * w4[4][j];
            a5 += h4 * w4[5][j];
            a6 += h4 * w4[6][j];
            a7 += h4 * w4[7][j];
        }
        float sr0 = (a0[0] + a0[1]) + (a0[2] + a0[3]);
        float sr1 = (a1[0] + a1[1]) + (a1[2] + a1[3]);
        float sr2 = (a2[0] + a2[1]) + (a2[2] + a2[3]);
        float sr3 = (a3[0] + a3[1]) + (a3[2] + a3[3]);
        float sr4 = (a4[0] + a4[1]) + (a4[2] + a4[3]);
        float sr5 = (a5[0] + a5[1]) + (a5[2] + a5[3]);
        float sr6 = (a6[0] + a6[1]) + (a6[2] + a6[3]);
        float sr7 = (a7[0] + a7[1]) + (a7[2] + a7[3]);
        // xor1 + xor2: DPP adds on the VALU pipe
        sr0 += dpp_xor1(sr0); sr1 += dpp_xor1(sr1); sr2 += dpp_xor1(sr2); sr3 += dpp_xor1(sr3);
        sr4 += dpp_xor1(sr4); sr5 += dpp_xor1(sr5); sr6 += dpp_xor1(sr6); sr7 += dpp_xor1(sr7);
        sr0 += dpp_xor2(sr0); sr1 += dpp_xor2(sr1); sr2 += dpp_xor2(sr2); sr3 += dpp_xor2(sr3);
        sr4 += dpp_xor2(sr4); sr5 += dpp_xor2(sr5); sr6 += dpp_xor2(sr6); sr7 += dpp_xor2(sr7);
        // narrow to own row (s[c]) and partner row (s[c^4]) with one select tree
        const bool b0 = c & 1, b1 = c & 2, b2 = c & 4;
        float u0 = b0 ? sr1 : sr0;
        float u1 = b0 ? sr3 : sr2;
        float u2 = b0 ? sr5 : sr4;
        float u3 = b0 ? sr7 : sr6;
        float v0 = b1 ? u1 : u0;
        float v1 = b1 ? u3 : u2;
        float own  = b2 ? v1 : v0;   // s[c]   : own row, own k-half
        float send = b2 ? v0 : v1;   // s[c^4] : partner's row, own k-half
        float other = __int_as_float(
            __builtin_amdgcn_ds_swizzle(__float_as_int(send), 0x101F)); // xor4
        float pre = own + other + xp_cur + bias;
        float e = __expf(2.0f * pre);             // tanh = 1 - 2/(e^{2x}+1)
        float hval = 1.0f - 2.0f * __builtin_amdgcn_rcpf(e + 1.0f);

        hsm[(t + 1) & 1][(row >> 5) * CH8 + (row & 31)] = hval;
        hh_prev = f2bf(hval);
        hl_prev = f2bf(hval - bf2f(hh_prev));
        xp_cur = xp_next;
        __syncthreads();                          // single barrier per step
    }
    ph[(size_t)(T - 1) * H] = hh_prev;
    pl[(size_t)(T - 1) * H] = hl_prev;
}

// ---------------------------------------------------------------------------
// K3: FC GEMM [32768,256] x [256,512] via 3-split bf16 MFMA.
// 128x128 tile, BK=64, 4 waves (2x2, 64x64 each), XOR-swizzled LDS.
// ---------------------------------------------------------------------------
__global__ __launch_bounds__(256, 2) void k_fc(
    const unsigned short* __restrict__ hs_hi, const unsigned short* __restrict__ hs_lo,
    const unsigned short* __restrict__ wfc_hi, const unsigned short* __restrict__ wfc_lo,
    const float* __restrict__ b_fc, float* __restrict__ out) {
    __shared__ short sAh[128 * 64], sAl[128 * 64], sBh[128 * 64], sBl[128 * 64];
    const int tid = threadIdx.x;
    const int bm = blockIdx.x >> 2, bn = blockIdx.x & 3;
    const int m0 = bm * 128, n0 = bn * 128;
    const int w = tid >> 6, lane = tid & 63;
    const int wm = w >> 1, wn = w & 1;
    const int l16 = lane & 15, g = lane >> 4;

    f32x4 acc[4][4];
#pragma unroll
    for (int a = 0; a < 4; ++a)
#pragma unroll
        for (int cc = 0; cc < 4; ++cc)
#pragma unroll
            for (int q = 0; q < 4; ++q) acc[a][cc][q] = 0.0f;

    for (int kt = 0; kt < 4; ++kt) {
        const int k0 = kt * 64;
#pragma unroll
        for (int s = 0; s < 4; ++s) {
            int cidx = tid + 256 * s;
            int r = cidx >> 3, slot = cidx & 7;
            int dst = r * 64 + ((slot ^ (r & 7)) << 3);
            size_t ga = (size_t)(m0 + r) * 256 + k0 + slot * 8;
            *(bf16x8*)&sAh[dst] = *(const bf16x8*)&hs_hi[ga];
            *(bf16x8*)&sAl[dst] = *(const bf16x8*)&hs_lo[ga];
            size_t gb = (size_t)(n0 + r) * 256 + k0 + slot * 8;
            *(bf16x8*)&sBh[dst] = *(const bf16x8*)&wfc_hi[gb];
            *(bf16x8*)&sBl[dst] = *(const bf16x8*)&wfc_lo[gb];
        }
        __syncthreads();
#pragma unroll
        for (int kc = 0; kc < 2; ++kc) {
            bf16x8 ah[4], al[4], bh[4], bl[4];
            const int slot = kc * 4 + g;
#pragma unroll
            for (int mi = 0; mi < 4; ++mi) {
                int r = wm * 64 + mi * 16 + l16;
                int off = r * 64 + ((slot ^ (r & 7)) << 3);
                ah[mi] = *(const bf16x8*)&sAh[off];
                al[mi] = *(const bf16x8*)&sAl[off];
            }
#pragma unroll
            for (int ni = 0; ni < 4; ++ni) {
                int r = wn * 64 + ni * 16 + l16;
                int off = r * 64 + ((slot ^ (r & 7)) << 3);
                bh[ni] = *(const bf16x8*)&sBh[off];
                bl[ni] = *(const bf16x8*)&sBl[off];
            }
#pragma unroll
            for (int mi = 0; mi < 4; ++mi)
#pragma unroll
                for (int ni = 0; ni < 4; ++ni) {
                    acc[mi][ni] = __builtin_amdgcn_mfma_f32_16x16x32_bf16(
                        ah[mi], bh[ni], acc[mi][ni], 0, 0, 0);
                    acc[mi][ni] = __builtin_amdgcn_mfma_f32_16x16x32_bf16(
                        ah[mi], bl[ni], acc[mi][ni], 0, 0, 0);
                    acc[mi][ni] = __builtin_amdgcn_mfma_f32_16x16x32_bf16(
                        al[mi], bh[ni], acc[mi][ni], 0, 0, 0);
                }
        }
        __syncthreads();
    }
#pragma unroll
    for (int ni = 0; ni < 4; ++ni) {
        int n = n0 + wn * 64 + ni * 16 + l16;
        float bfc = b_fc[n];
#pragma unroll
        for (int mi = 0; mi < 4; ++mi) {
#pragma unroll
            for (int q = 0; q < 4; ++q) {
                int m = m0 + wm * 64 + mi * 16 + g * 4 + q;
                out[(size_t)m * O + n] = acc[mi][ni][q] + bfc;
            }
        }
    }
}

extern "C" void kernel_launch(void* const* d_in, const int* in_sizes, int n_in,
                              void* d_out, int out_size, void* d_ws, size_t ws_size,
                              hipStream_t stream) {
    (void)in_sizes; (void)n_in; (void)out_size; (void)ws_size;
    const int*   x    = (const int*)d_in[0];
    const float* Wih  = (const float*)d_in[1];
    const float* Whh  = (const float*)d_in[2];
    const float* bih  = (const float*)d_in[3];
    const float* bhh  = (const float*)d_in[4];
    const float* Wfc  = (const float*)d_in[5];
    const float* bfc  = (const float*)d_in[6];
    float* out = (float*)d_out;

    char* ws = (char*)d_ws;
    float*          WihT = (float*)ws;                                  // 4 MB
    unsigned short* wfch = (unsigned short*)(ws + 4194304);             // 256 KB
    unsigned short* wfcl = (unsigned short*)(ws + 4194304 + 262144);    // 256 KB
    unsigned short* hsh  = (unsigned short*)(ws + 4718592);             // 16 MB
    unsigned short* hsl  = (unsigned short*)(ws + 4718592 + 16777216);  // 16 MB

    k_transpose<<<256, 256, 0, stream>>>(Wih, WihT);
    k_prep<<<512, 256, 0, stream>>>(Wfc, wfch, wfcl);
    k_rnn<<<64, 256, 0, stream>>>(x, WihT, Whh, bih, bhh, hsh, hsl);
    k_fc<<<1024, 256, 0, stream>>>(hsh, hsl, wfch, wfcl, bfc, out);
}

// Round 5
// 348.647 us; speedup vs baseline: 1.4314x; 1.4314x over previous
//
#include <hip/hip_runtime.h>

#define V 4096
#define H 256
#define O 512
#define B 64
#define T 512

typedef __attribute__((ext_vector_type(8))) short bf16x8;
typedef __attribute__((ext_vector_type(4))) float f32x4;
typedef __attribute__((ext_vector_type(2))) float f32x2;

__device__ __forceinline__ unsigned short f2bf(float f) {
    unsigned int u = __float_as_uint(f);
    u += 0x7fffu + ((u >> 16) & 1u);   // round-to-nearest-even
    return (unsigned short)(u >> 16);
}
__device__ __forceinline__ float bf2f(unsigned short s) {
    return __uint_as_float(((unsigned int)s) << 16);
}

// DPP cross-lane adds (VALU pipe, zero DS cost)
__device__ __forceinline__ float dpp_xor1(float v) {
    int i = __float_as_int(v);
    return __int_as_float(__builtin_amdgcn_update_dpp(i, i, 0xB1, 0xf, 0xf, true)); // quad_perm[1,0,3,2]
}
__device__ __forceinline__ float dpp_xor2(float v) {
    int i = __float_as_int(v);
    return __int_as_float(__builtin_amdgcn_update_dpp(i, i, 0x4E, 0xf, 0xf, true)); // quad_perm[2,3,0,1]
}
__device__ __forceinline__ float dpp_ror8(float v) {
    // row_ror:8 — within each row of 16 lanes, lane c reads lane c^8 (rot8==xor8 in 16)
    int i = __float_as_int(v);
    return __int_as_float(__builtin_amdgcn_update_dpp(i, i, 0x128, 0xf, 0xf, true));
}

// ---------------------------------------------------------------------------
// K1a: transpose W_ih [H][V] -> WihT [V][H] (coalesced per-step gather rows).
// ---------------------------------------------------------------------------
__global__ __launch_bounds__(256) void k_transpose(const float* __restrict__ Wih,
                                                   float* __restrict__ WihT) {
    __shared__ float tile[64][65];
    const int bi = blockIdx.x & 3;
    const int bv = blockIdx.x >> 2;
    const int tx = threadIdx.x & 63, ty = threadIdx.x >> 6;
#pragma unroll
    for (int s = 0; s < 16; ++s) {
        int r = ty + 4 * s;
        tile[r][tx] = Wih[(size_t)(bi * 64 + r) * V + bv * 64 + tx];
    }
    __syncthreads();
#pragma unroll
    for (int s = 0; s < 16; ++s) {
        int r = ty + 4 * s;
        WihT[(size_t)(bv * 64 + r) * H + bi * 64 + tx] = tile[tx][r];
    }
}

// ---------------------------------------------------------------------------
// K1b: split W_fc into bf16 hi + bf16 lo for the 3-MFMA FC.
// ---------------------------------------------------------------------------
__global__ __launch_bounds__(256) void k_prep(const float* __restrict__ Wfc,
                                              unsigned short* __restrict__ hi,
                                              unsigned short* __restrict__ lo) {
    int i = blockIdx.x * 256 + threadIdx.x;
    float w = Wfc[i];
    unsigned short h = f2bf(w);
    hi[i] = h;
    lo[i] = f2bf(w - bf2f(h));
}

// ---------------------------------------------------------------------------
// K2: persistent RNN. 64 blocks x 512 threads, exactly 2 waves/EU (VGPR cap
// 256). Thread (g = tid>>4, c = tid&15): rows 8g..8g+7, k-16th c (16 terms).
// Weights: 64 x f32x2 = 128 VGPRs (fits arch cap with ~60 working regs —
// R4's 256-float request overflowed the 256 arch-VGPR limit into AGPR moves).
// h-broadcast: 4 ds_read_b128/thread (32 wave-instrs/CU/step, the R3 wall of
// 128 is cut 4x). Reduce over 16-lane k-split: DPP xor1/xor2 + selects,
// ds_swizzle xor4 (x2), DPP row_ror:8 for xor8 (VALU, free of DS pipe).
// Lanes c and c+8 duplicate-finalize row 8g+(c&7); c<8 stores hi, c>=8 lo.
// ---------------------------------------------------------------------------
#define CH16 20   // chunk stride in floats (16 data + 4 pad): 16 bases spread 2-way max

__global__ __launch_bounds__(512)
__attribute__((amdgpu_waves_per_eu(2, 2)))
void k_rnn(
    const int* __restrict__ x, const float* __restrict__ WihT,
    const float* __restrict__ Whh, const float* __restrict__ b_ih,
    const float* __restrict__ b_hh,
    unsigned short* __restrict__ hs_hi, unsigned short* __restrict__ hs_lo) {
    __shared__ float hsm[2][16 * CH16];
    __shared__ int xs[T];
    const int b = blockIdx.x;
    const int tid = threadIdx.x;
    const int g = tid >> 4;        // row-group 0..31 (8 rows each)
    const int c = tid & 15;        // k-16th 0..15 (16 terms)
    const int cr = c & 7;          // row within group this lane finalizes
    const int row = 8 * g + cr;
    const int k0 = 16 * c;

    // W_hh rows 8g..8g+7, k in [k0, k0+16): 64 f32x2 = 128 VGPRs
    f32x2 w2[8][8];
#pragma unroll
    for (int r = 0; r < 8; ++r) {
        const f32x2* wr = (const f32x2*)(Whh + (size_t)(8 * g + r) * H + k0);
#pragma unroll
        for (int q = 0; q < 8; ++q) w2[r][q] = wr[q];
    }
#pragma unroll
    for (int r = 0; r < 8; ++r)
#pragma unroll
        for (int q = 0; q < 8; ++q)
            asm volatile("" : "+v"(w2[r][q]));   // opaque: no remat

    xs[tid] = x[b * T + tid];
    if (tid < 16 * CH16) hsm[0][tid] = 0.0f;
    const float bias = b_ih[row] + b_hh[row];
    __syncthreads();

    unsigned short* ph = hs_hi + (size_t)b * T * H + row;
    unsigned short* pl = hs_lo + (size_t)b * T * H + row;

    float xp_cur = WihT[(size_t)xs[0] * H + row];
    unsigned short h_prev = 0;     // c<8 lanes carry hi, c>=8 carry lo

    for (int t = 0; t < T; ++t) {
        // store h_{t-1}: duplicates split the work; drains under this dot
        if (t > 0) {
            if (c < 8) ph[(size_t)(t - 1) * H] = h_prev;
            else       pl[(size_t)(t - 1) * H] = h_prev;
        }
        int tn = (t + 1 < T) ? t + 1 : t;
        float xp_next = WihT[(size_t)xs[tn] * H + row];

        // 4 x ds_read_b128: 16 h values for this lane's k-slice
        const f32x4* hv = (const f32x4*)&hsm[t & 1][c * CH16];
        f32x4 q0 = hv[0], q1 = hv[1], q2 = hv[2], q3 = hv[3];
        f32x2 h2[8] = {{q0[0], q0[1]}, {q0[2], q0[3]}, {q1[0], q1[1]}, {q1[2], q1[3]},
                       {q2[0], q2[1]}, {q2[2], q2[3]}, {q3[0], q3[1]}, {q3[2], q3[3]}};
        f32x2 a0 = {0,0}, a1 = {0,0}, a2 = {0,0}, a3 = {0,0};
        f32x2 a4 = {0,0}, a5 = {0,0}, a6 = {0,0}, a7 = {0,0};
#pragma unroll
        for (int q = 0; q < 8; ++q) {
            a0 += h2[q] * w2[0][q];
            a1 += h2[q] * w2[1][q];
            a2 += h2[q] * w2[2][q];
            a3 += h2[q] * w2[3][q];
            a4 += h2[q] * w2[4][q];
            a5 += h2[q] * w2[5][q];
            a6 += h2[q] * w2[6][q];
            a7 += h2[q] * w2[7][q];
        }
        float s0 = a0[0] + a0[1], s1 = a1[0] + a1[1];
        float s2 = a2[0] + a2[1], s3 = a3[0] + a3[1];
        float s4 = a4[0] + a4[1], s5 = a5[0] + a5[1];
        float s6 = a6[0] + a6[1], s7 = a7[0] + a7[1];
        // level 1 (k): DPP adds; keep rows with r&1 == c&1
        s0 += dpp_xor1(s0); s1 += dpp_xor1(s1); s2 += dpp_xor1(s2); s3 += dpp_xor1(s3);
        s4 += dpp_xor1(s4); s5 += dpp_xor1(s5); s6 += dpp_xor1(s6); s7 += dpp_xor1(s7);
        const bool b0 = c & 1, b1 = c & 2, b2 = c & 4;
        float u0 = b0 ? s1 : s0;
        float u1 = b0 ? s3 : s2;
        float u2 = b0 ? s5 : s4;
        float u3 = b0 ? s7 : s6;
        // level 2: DPP adds; keep rows with r&2 == c&2
        u0 += dpp_xor2(u0); u1 += dpp_xor2(u1); u2 += dpp_xor2(u2); u3 += dpp_xor2(u3);
        float v0 = b1 ? u1 : u0;
        float v1 = b1 ? u3 : u2;
        // level 4: ds_swizzle xor4 (2 DS ops); keep row with r&4 == c&4
        v0 += __int_as_float(__builtin_amdgcn_ds_swizzle(__float_as_int(v0), 0x101F));
        v1 += __int_as_float(__builtin_amdgcn_ds_swizzle(__float_as_int(v1), 0x101F));
        float own = b2 ? v1 : v0;      // row = c&7, k-half per bit3 of c
        // level 8: DPP row_ror:8 == xor8 within the 16-lane group (VALU)
        own += dpp_ror8(own);

        float pre = own + xp_cur + bias;
        float e = __expf(2.0f * pre);              // tanh = 1 - 2/(e^{2x}+1)
        float hval = 1.0f - 2.0f * __builtin_amdgcn_rcpf(e + 1.0f);

        if (c < 8)
            hsm[(t + 1) & 1][(row >> 4) * CH16 + (row & 15)] = hval;
        unsigned short hh = f2bf(hval);
        h_prev = (c < 8) ? hh : f2bf(hval - bf2f(hh));
        xp_cur = xp_next;
        __syncthreads();                           // single barrier per step
    }
    if (c < 8) ph[(size_t)(T - 1) * H] = h_prev;
    else       pl[(size_t)(T - 1) * H] = h_prev;
}

// ---------------------------------------------------------------------------
// K3: FC GEMM [32768,256] x [256,512] via 3-split bf16 MFMA.
// 128x128 tile, BK=64, 4 waves (2x2, 64x64 each), XOR-swizzled LDS.
// ---------------------------------------------------------------------------
__global__ __launch_bounds__(256, 2) void k_fc(
    const unsigned short* __restrict__ hs_hi, const unsigned short* __restrict__ hs_lo,
    const unsigned short* __restrict__ wfc_hi, const unsigned short* __restrict__ wfc_lo,
    const float* __restrict__ b_fc, float* __restrict__ out) {
    __shared__ short sAh[128 * 64], sAl[128 * 64], sBh[128 * 64], sBl[128 * 64];
    const int tid = threadIdx.x;
    const int bm = blockIdx.x >> 2, bn = blockIdx.x & 3;
    const int m0 = bm * 128, n0 = bn * 128;
    const int w = tid >> 6, lane = tid & 63;
    const int wm = w >> 1, wn = w & 1;
    const int l16 = lane & 15, g = lane >> 4;

    f32x4 acc[4][4];
#pragma unroll
    for (int a = 0; a < 4; ++a)
#pragma unroll
        for (int cc = 0; cc < 4; ++cc)
#pragma unroll
            for (int q = 0; q < 4; ++q) acc[a][cc][q] = 0.0f;

    for (int kt = 0; kt < 4; ++kt) {
        const int k0 = kt * 64;
#pragma unroll
        for (int s = 0; s < 4; ++s) {
            int cidx = tid + 256 * s;
            int r = cidx >> 3, slot = cidx & 7;
            int dst = r * 64 + ((slot ^ (r & 7)) << 3);
            size_t ga = (size_t)(m0 + r) * 256 + k0 + slot * 8;
            *(bf16x8*)&sAh[dst] = *(const bf16x8*)&hs_hi[ga];
            *(bf16x8*)&sAl[dst] = *(const bf16x8*)&hs_lo[ga];
            size_t gb = (size_t)(n0 + r) * 256 + k0 + slot * 8;
            *(bf16x8*)&sBh[dst] = *(const bf16x8*)&wfc_hi[gb];
            *(bf16x8*)&sBl[dst] = *(const bf16x8*)&wfc_lo[gb];
        }
        __syncthreads();
#pragma unroll
        for (int kc = 0; kc < 2; ++kc) {
            bf16x8 ah[4], al[4], bh[4], bl[4];
            const int slot = kc * 4 + g;
#pragma unroll
            for (int mi = 0; mi < 4; ++mi) {
                int r = wm * 64 + mi * 16 + l16;
                int off = r * 64 + ((slot ^ (r & 7)) << 3);
                ah[mi] = *(const bf16x8*)&sAh[off];
                al[mi] = *(const bf16x8*)&sAl[off];
            }
#pragma unroll
            for (int ni = 0; ni < 4; ++ni) {
                int r = wn * 64 + ni * 16 + l16;
                int off = r * 64 + ((slot ^ (r & 7)) << 3);
                bh[ni] = *(const bf16x8*)&sBh[off];
                bl[ni] = *(const bf16x8*)&sBl[off];
            }
#pragma unroll
            for (int mi = 0; mi < 4; ++mi)
#pragma unroll
                for (int ni = 0; ni < 4; ++ni) {
                    acc[mi][ni] = __builtin_amdgcn_mfma_f32_16x16x32_bf16(
                        ah[mi], bh[ni], acc[mi][ni], 0, 0, 0);
                    acc[mi][ni] = __builtin_amdgcn_mfma_f32_16x16x32_bf16(
                        ah[mi], bl[ni], acc[mi][ni], 0, 0, 0);
                    acc[mi][ni] = __builtin_amdgcn_mfma_f32_16x16x32_bf16(
                        al[mi], bh[ni], acc[mi][ni], 0, 0, 0);
                }
        }
        __syncthreads();
    }
#pragma unroll
    for (int ni = 0; ni < 4; ++ni) {
        int n = n0 + wn * 64 + ni * 16 + l16;
        float bfc = b_fc[n];
#pragma unroll
        for (int mi = 0; mi < 4; ++mi) {
#pragma unroll
            for (int q = 0; q < 4; ++q) {
                int m = m0 + wm * 64 + mi * 16 + g * 4 + q;
                out[(size_t)m * O + n] = acc[mi][ni][q] + bfc;
            }
        }
    }
}

extern "C" void kernel_launch(void* const* d_in, const int* in_sizes, int n_in,
                              void* d_out, int out_size, void* d_ws, size_t ws_size,
                              hipStream_t stream) {
    (void)in_sizes; (void)n_in; (void)out_size; (void)ws_size;
    const int*   x    = (const int*)d_in[0];
    const float* Wih  = (const float*)d_in[1];
    const float* Whh  = (const float*)d_in[2];
    const float* bih  = (const float*)d_in[3];
    const float* bhh  = (const float*)d_in[4];
    const float* Wfc  = (const float*)d_in[5];
    const float* bfc  = (const float*)d_in[6];
    float* out = (float*)d_out;

    char* ws = (char*)d_ws;
    float*          WihT = (float*)ws;                                  // 4 MB
    unsigned short* wfch = (unsigned short*)(ws + 4194304);             // 256 KB
    unsigned short* wfcl = (unsigned short*)(ws + 4194304 + 262144);    // 256 KB
    unsigned short* hsh  = (unsigned short*)(ws + 4718592);             // 16 MB
    unsigned short* hsl  = (unsigned short*)(ws + 4718592 + 16777216);  // 16 MB

    k_transpose<<<256, 256, 0, stream>>>(Wih, WihT);
    k_prep<<<512, 256, 0, stream>>>(Wfc, wfch, wfcl);
    k_rnn<<<64, 512, 0, stream>>>(x, WihT, Whh, bih, bhh, hsh, hsl);
    k_fc<<<1024, 256, 0, stream>>>(hsh, hsl, wfch, wfcl, bfc, out);
}

// Round 6
// 344.497 us; speedup vs baseline: 1.4486x; 1.0120x over previous
//
#include <hip/hip_runtime.h>

#define V 4096
#define H 256
#define O 512
#define B 64
#define T 512

typedef __attribute__((ext_vector_type(8))) short bf16x8;
typedef __attribute__((ext_vector_type(4))) float f32x4;
typedef __attribute__((ext_vector_type(2))) float f32x2;

__device__ __forceinline__ unsigned short f2bf(float f) {
    unsigned int u = __float_as_uint(f);
    u += 0x7fffu + ((u >> 16) & 1u);   // round-to-nearest-even
    return (unsigned short)(u >> 16);
}
__device__ __forceinline__ float bf2f(unsigned short s) {
    return __uint_as_float(((unsigned int)s) << 16);
}

// DPP cross-lane adds (VALU pipe, zero DS cost)
__device__ __forceinline__ float dpp_xor1(float v) {
    int i = __float_as_int(v);
    return __int_as_float(__builtin_amdgcn_update_dpp(i, i, 0xB1, 0xf, 0xf, true)); // quad_perm[1,0,3,2]
}
__device__ __forceinline__ float dpp_xor2(float v) {
    int i = __float_as_int(v);
    return __int_as_float(__builtin_amdgcn_update_dpp(i, i, 0x4E, 0xf, 0xf, true)); // quad_perm[2,3,0,1]
}
__device__ __forceinline__ float dpp_ror8(float v) {
    // row_ror:8 — within each 16-lane row, lane c reads lane c^8
    int i = __float_as_int(v);
    return __int_as_float(__builtin_amdgcn_update_dpp(i, i, 0x128, 0xf, 0xf, true));
}

// ---------------------------------------------------------------------------
// K1a: transpose W_ih [H][V] -> WihT [V][H] (coalesced per-step gather rows).
// ---------------------------------------------------------------------------
__global__ __launch_bounds__(256) void k_transpose(const float* __restrict__ Wih,
                                                   float* __restrict__ WihT) {
    __shared__ float tile[64][65];
    const int bi = blockIdx.x & 3;
    const int bv = blockIdx.x >> 2;
    const int tx = threadIdx.x & 63, ty = threadIdx.x >> 6;
#pragma unroll
    for (int s = 0; s < 16; ++s) {
        int r = ty + 4 * s;
        tile[r][tx] = Wih[(size_t)(bi * 64 + r) * V + bv * 64 + tx];
    }
    __syncthreads();
#pragma unroll
    for (int s = 0; s < 16; ++s) {
        int r = ty + 4 * s;
        WihT[(size_t)(bv * 64 + r) * H + bi * 64 + tx] = tile[tx][r];
    }
}

// ---------------------------------------------------------------------------
// K1b: split W_fc into bf16 hi + bf16 lo for the 3-MFMA FC.
// ---------------------------------------------------------------------------
__global__ __launch_bounds__(256) void k_prep(const float* __restrict__ Wfc,
                                              unsigned short* __restrict__ hi,
                                              unsigned short* __restrict__ lo) {
    int i = blockIdx.x * 256 + threadIdx.x;
    float w = Wfc[i];
    unsigned short h = f2bf(w);
    hi[i] = h;
    lo[i] = f2bf(w - bf2f(h));
}

// ---------------------------------------------------------------------------
// K2: persistent RNN (R5 structure). 64 blocks x 512 threads, 2 waves/EU.
// Thread (g = tid>>4, c = tid&15): rows 8g..8g+7, k-16th c (16 terms).
// R6 changes:
//  (a) relaxed barrier: s_waitcnt lgkmcnt(0) + raw s_barrier — NO vmcnt(0)
//      drain, so the xp gather and hs stores stay in flight across steps
//      (T4 counted-wait principle; __syncthreads was serializing an HBM-miss
//      gather into every step's barrier).
//  (b) nontemporal hs stores: the 32 MB hs stream no longer evicts the 4 MB
//      WihT from per-XCD L2 -> gathers become L2 hits (FETCH_SIZE check).
// ---------------------------------------------------------------------------
#define CH16 20   // chunk stride in floats (16 data + 4 pad)

__global__ __launch_bounds__(512)
__attribute__((amdgpu_waves_per_eu(2, 2)))
void k_rnn(
    const int* __restrict__ x, const float* __restrict__ WihT,
    const float* __restrict__ Whh, const float* __restrict__ b_ih,
    const float* __restrict__ b_hh,
    unsigned short* __restrict__ hs_hi, unsigned short* __restrict__ hs_lo) {
    __shared__ float hsm[2][16 * CH16];
    __shared__ int xs[T];
    const int b = blockIdx.x;
    const int tid = threadIdx.x;
    const int g = tid >> 4;        // row-group 0..31 (8 rows each)
    const int c = tid & 15;        // k-16th 0..15 (16 terms)
    const int cr = c & 7;          // row within group this lane finalizes
    const int row = 8 * g + cr;
    const int k0 = 16 * c;

    // W_hh rows 8g..8g+7, k in [k0, k0+16): 64 f32x2 = 128 VGPRs
    f32x2 w2[8][8];
#pragma unroll
    for (int r = 0; r < 8; ++r) {
        const f32x2* wr = (const f32x2*)(Whh + (size_t)(8 * g + r) * H + k0);
#pragma unroll
        for (int q = 0; q < 8; ++q) w2[r][q] = wr[q];
    }
#pragma unroll
    for (int r = 0; r < 8; ++r)
#pragma unroll
        for (int q = 0; q < 8; ++q)
            asm volatile("" : "+v"(w2[r][q]));   // opaque: no remat

    xs[tid] = x[b * T + tid];
    if (tid < 16 * CH16) hsm[0][tid] = 0.0f;
    const float bias = b_ih[row] + b_hh[row];
    __syncthreads();   // full barrier once (init visibility incl. globals)

    unsigned short* ph = hs_hi + (size_t)b * T * H + row;
    unsigned short* pl = hs_lo + (size_t)b * T * H + row;

    float xp_cur = WihT[(size_t)xs[0] * H + row];
    unsigned short h_prev = 0;     // c<8 lanes carry hi, c>=8 carry lo

    for (int t = 0; t < T; ++t) {
        // store h_{t-1}: nontemporal (don't thrash WihT in L2); drains async
        if (t > 0) {
            if (c < 8) __builtin_nontemporal_store(h_prev, &ph[(size_t)(t - 1) * H]);
            else       __builtin_nontemporal_store(h_prev, &pl[(size_t)(t - 1) * H]);
        }
        int tn = (t + 1 < T) ? t + 1 : t;
        float xp_next = WihT[(size_t)xs[tn] * H + row];

        // 4 x ds_read_b128: 16 h values for this lane's k-slice
        const f32x4* hv = (const f32x4*)&hsm[t & 1][c * CH16];
        f32x4 q0 = hv[0], q1 = hv[1], q2 = hv[2], q3 = hv[3];
        f32x2 h2[8] = {{q0[0], q0[1]}, {q0[2], q0[3]}, {q1[0], q1[1]}, {q1[2], q1[3]},
                       {q2[0], q2[1]}, {q2[2], q2[3]}, {q3[0], q3[1]}, {q3[2], q3[3]}};
        f32x2 a0 = {0,0}, a1 = {0,0}, a2 = {0,0}, a3 = {0,0};
        f32x2 a4 = {0,0}, a5 = {0,0}, a6 = {0,0}, a7 = {0,0};
#pragma unroll
        for (int q = 0; q < 8; ++q) {
            a0 += h2[q] * w2[0][q];
            a1 += h2[q] * w2[1][q];
            a2 += h2[q] * w2[2][q];
            a3 += h2[q] * w2[3][q];
            a4 += h2[q] * w2[4][q];
            a5 += h2[q] * w2[5][q];
            a6 += h2[q] * w2[6][q];
            a7 += h2[q] * w2[7][q];
        }
        float s0 = a0[0] + a0[1], s1 = a1[0] + a1[1];
        float s2 = a2[0] + a2[1], s3 = a3[0] + a3[1];
        float s4 = a4[0] + a4[1], s5 = a5[0] + a5[1];
        float s6 = a6[0] + a6[1], s7 = a7[0] + a7[1];
        // level 1 (k): DPP adds; keep rows with r&1 == c&1
        s0 += dpp_xor1(s0); s1 += dpp_xor1(s1); s2 += dpp_xor1(s2); s3 += dpp_xor1(s3);
        s4 += dpp_xor1(s4); s5 += dpp_xor1(s5); s6 += dpp_xor1(s6); s7 += dpp_xor1(s7);
        const bool b0 = c & 1, b1 = c & 2, b2 = c & 4;
        float u0 = b0 ? s1 : s0;
        float u1 = b0 ? s3 : s2;
        float u2 = b0 ? s5 : s4;
        float u3 = b0 ? s7 : s6;
        // level 2: DPP adds; keep rows with r&2 == c&2
        u0 += dpp_xor2(u0); u1 += dpp_xor2(u1); u2 += dpp_xor2(u2); u3 += dpp_xor2(u3);
        float v0 = b1 ? u1 : u0;
        float v1 = b1 ? u3 : u2;
        // level 4: ds_swizzle xor4 (2 DS ops); keep row with r&4 == c&4
        v0 += __int_as_float(__builtin_amdgcn_ds_swizzle(__float_as_int(v0), 0x101F));
        v1 += __int_as_float(__builtin_amdgcn_ds_swizzle(__float_as_int(v1), 0x101F));
        float own = b2 ? v1 : v0;      // row = c&7, k-half per bit3 of c
        // level 8: DPP row_ror:8 == xor8 within the 16-lane group (VALU)
        own += dpp_ror8(own);

        float pre = own + xp_cur + bias;
        float e = __expf(2.0f * pre);              // tanh = 1 - 2/(e^{2x}+1)
        float hval = 1.0f - 2.0f * __builtin_amdgcn_rcpf(e + 1.0f);

        if (c < 8)
            hsm[(t + 1) & 1][(row >> 4) * CH16 + (row & 15)] = hval;
        unsigned short hh = f2bf(hval);
        h_prev = (c < 8) ? hh : f2bf(hval - bf2f(hh));
        xp_cur = xp_next;

        // relaxed barrier: LDS visibility only, no vmcnt drain
        asm volatile("s_waitcnt lgkmcnt(0)" ::: "memory");
        __builtin_amdgcn_s_barrier();
        asm volatile("" ::: "memory");
    }
    if (c < 8) ph[(size_t)(T - 1) * H] = h_prev;
    else       pl[(size_t)(T - 1) * H] = h_prev;
}

// ---------------------------------------------------------------------------
// K3: FC GEMM [32768,256] x [256,512] via 3-split bf16 MFMA.
// 128x128 tile, BK=64, 4 waves (2x2, 64x64 each), XOR-swizzled LDS.
// ---------------------------------------------------------------------------
__global__ __launch_bounds__(256, 2) void k_fc(
    const unsigned short* __restrict__ hs_hi, const unsigned short* __restrict__ hs_lo,
    const unsigned short* __restrict__ wfc_hi, const unsigned short* __restrict__ wfc_lo,
    const float* __restrict__ b_fc, float* __restrict__ out) {
    __shared__ short sAh[128 * 64], sAl[128 * 64], sBh[128 * 64], sBl[128 * 64];
    const int tid = threadIdx.x;
    const int bm = blockIdx.x >> 2, bn = blockIdx.x & 3;
    const int m0 = bm * 128, n0 = bn * 128;
    const int w = tid >> 6, lane = tid & 63;
    const int wm = w >> 1, wn = w & 1;
    const int l16 = lane & 15, g = lane >> 4;

    f32x4 acc[4][4];
#pragma unroll
    for (int a = 0; a < 4; ++a)
#pragma unroll
        for (int cc = 0; cc < 4; ++cc)
#pragma unroll
            for (int q = 0; q < 4; ++q) acc[a][cc][q] = 0.0f;

    for (int kt = 0; kt < 4; ++kt) {
        const int k0 = kt * 64;
#pragma unroll
        for (int s = 0; s < 4; ++s) {
            int cidx = tid + 256 * s;
            int r = cidx >> 3, slot = cidx & 7;
            int dst = r * 64 + ((slot ^ (r & 7)) << 3);
            size_t ga = (size_t)(m0 + r) * 256 + k0 + slot * 8;
            *(bf16x8*)&sAh[dst] = *(const bf16x8*)&hs_hi[ga];
            *(bf16x8*)&sAl[dst] = *(const bf16x8*)&hs_lo[ga];
            size_t gb = (size_t)(n0 + r) * 256 + k0 + slot * 8;
            *(bf16x8*)&sBh[dst] = *(const bf16x8*)&wfc_hi[gb];
            *(bf16x8*)&sBl[dst] = *(const bf16x8*)&wfc_lo[gb];
        }
        __syncthreads();
#pragma unroll
        for (int kc = 0; kc < 2; ++kc) {
            bf16x8 ah[4], al[4], bh[4], bl[4];
            const int slot = kc * 4 + g;
#pragma unroll
            for (int mi = 0; mi < 4; ++mi) {
                int r = wm * 64 + mi * 16 + l16;
                int off = r * 64 + ((slot ^ (r & 7)) << 3);
                ah[mi] = *(const bf16x8*)&sAh[off];
                al[mi] = *(const bf16x8*)&sAl[off];
            }
#pragma unroll
            for (int ni = 0; ni < 4; ++ni) {
                int r = wn * 64 + ni * 16 + l16;
                int off = r * 64 + ((slot ^ (r & 7)) << 3);
                bh[ni] = *(const bf16x8*)&sBh[off];
                bl[ni] = *(const bf16x8*)&sBl[off];
            }
#pragma unroll
            for (int mi = 0; mi < 4; ++mi)
#pragma unroll
                for (int ni = 0; ni < 4; ++ni) {
                    acc[mi][ni] = __builtin_amdgcn_mfma_f32_16x16x32_bf16(
                        ah[mi], bh[ni], acc[mi][ni], 0, 0, 0);
                    acc[mi][ni] = __builtin_amdgcn_mfma_f32_16x16x32_bf16(
                        ah[mi], bl[ni], acc[mi][ni], 0, 0, 0);
                    acc[mi][ni] = __builtin_amdgcn_mfma_f32_16x16x32_bf16(
                        al[mi], bh[ni], acc[mi][ni], 0, 0, 0);
                }
        }
        __syncthreads();
    }
#pragma unroll
    for (int ni = 0; ni < 4; ++ni) {
        int n = n0 + wn * 64 + ni * 16 + l16;
        float bfc = b_fc[n];
#pragma unroll
        for (int mi = 0; mi < 4; ++mi) {
#pragma unroll
            for (int q = 0; q < 4; ++q) {
                int m = m0 + wm * 64 + mi * 16 + g * 4 + q;
                out[(size_t)m * O + n] = acc[mi][ni][q] + bfc;
            }
        }
    }
}

extern "C" void kernel_launch(void* const* d_in, const int* in_sizes, int n_in,
                              void* d_out, int out_size, void* d_ws, size_t ws_size,
                              hipStream_t stream) {
    (void)in_sizes; (void)n_in; (void)out_size; (void)ws_size;
    const int*   x    = (const int*)d_in[0];
    const float* Wih  = (const float*)d_in[1];
    const float* Whh  = (const float*)d_in[2];
    const float* bih  = (const float*)d_in[3];
    const float* bhh  = (const float*)d_in[4];
    const float* Wfc  = (const float*)d_in[5];
    const float* bfc  = (const float*)d_in[6];
    float* out = (float*)d_out;

    char* ws = (char*)d_ws;
    float*          WihT = (float*)ws;                                  // 4 MB
    unsigned short* wfch = (unsigned short*)(ws + 4194304);             // 256 KB
    unsigned short* wfcl = (unsigned short*)(ws + 4194304 + 262144);    // 256 KB
    unsigned short* hsh  = (unsigned short*)(ws + 4718592);             // 16 MB
    unsigned short* hsl  = (unsigned short*)(ws + 4718592 + 16777216);  // 16 MB

    k_transpose<<<256, 256, 0, stream>>>(Wih, WihT);
    k_prep<<<512, 256, 0, stream>>>(Wfc, wfch, wfcl);
    k_rnn<<<64, 512, 0, stream>>>(x, WihT, Whh, bih, bhh, hsh, hsl);
    k_fc<<<1024, 256, 0, stream>>>(hsh, hsl, wfch, wfcl, bfc, out);
}